// Round 6
// baseline (1349.001 us; speedup 1.0000x reference)
//
#include <hip/hip_runtime.h>
#include <hip/hip_cooperative_groups.h>
#include <math.h>

namespace cg = cooperative_groups;

#define NB 16
#define NN 1000
#define NT 16000          // NB*NN total nodes
#define NE 16000          // edges per graph
#define EBASE 256000      // NB*NE
#define ETOT 272000       // EBASE + NT self loops
#define F1 1024           // H1*C1
#define EMB 64
#define HID 128
#define KTOT 64000        // N*EMB mlp1 reduction length
#define NBLK 512          // cooperative grid size (co-resident: 2 blocks/CU needed, 4 guaranteed)

typedef unsigned short ushort_t;
typedef unsigned int uint_t;
typedef __attribute__((ext_vector_type(8))) _Float16 half8;
typedef __attribute__((ext_vector_type(4))) float float4_;
typedef __attribute__((ext_vector_type(2))) float float2_;
typedef __attribute__((ext_vector_type(2))) uint_t uint2_;

// ---- scrambled edge mapping (faithful to reference row-major reshape) ----
__device__ __forceinline__ int src_of(const int* ei, int j) {
    if (j < EBASE) return ei[j] + (j / 32000) * 1000;
    return j - EBASE;
}
__device__ __forceinline__ int dst_of(const int* ei, int j) {
    if (j < EBASE) return ei[EBASE + j] + (8 + j / 32000) * 1000;
    return j - EBASE;
}

__device__ __forceinline__ float lrelu02(float r) { return r >= 0.f ? r : 0.2f * r; }
__device__ __forceinline__ float elu1(float v)    { return v > 0.f ? v : expm1f(v); }
__device__ __forceinline__ ushort_t f2h(float f) {
    _Float16 h = (_Float16)f;           // v_cvt_f16_f32, RTE
    union { _Float16 h; ushort_t u; } c; c.h = h; return c.u;
}

struct GParams {
    const float *actions, *nf;
    const int   *ei;
    const float *W1, *as1w, *ad1w, *b1;
    const float *W2, *as2w, *ad2w, *b2;
    const float *mw1, *mb1, *mw2, *mb2, *ow, *ob;
    float *out;
    float *x4, *h2, *x2t, *as1, *ad1, *a2s, *a2d, *wa_s, *wa_d, *y1part, *y1sum, *y2;
    ushort_t *x1h, *w2t;
    int *counts, *offs, *cursor, *esrc;
};

__global__ __launch_bounds__(256, 4) void k_mega(GParams p) {
    cg::grid_group grid = cg::this_grid();
    __shared__ union {
        int   scan[256];
        float tile[64][65];      // 16.6 KB (max member)
        float smb[16][8][3];
        float red[NB * HID];
    } sm;
    const int t = threadIdx.x;
    const int bid = blockIdx.x;
    const int wave = t >> 6, lane = t & 63;

    // ================= P0: zero counts/y1sum + wa precontract =================
    for (int i = bid * 256 + t; i < NT; i += NBLK * 256) p.counts[i] = 0;
    for (int i = bid * 256 + t; i < NB * HID; i += NBLK * 256) p.y1sum[i] = 0.f;
    if (bid == 1 && t < 24) {
        int k = t / 8, h = t % 8;
        float ss = 0.f, dd = 0.f;
        for (int c = 0; c < 128; ++c) {
            float w = p.W1[k * F1 + h * 128 + c];
            ss += w * p.as1w[h * 128 + c];
            dd += w * p.ad1w[h * 128 + c];
        }
        p.wa_s[k * 8 + h] = ss; p.wa_d[k * 8 + h] = dd;
    }
    __threadfence();
    grid.sync();

    // ================= P1: CSR histogram =================
    for (int j = bid * 256 + t; j < ETOT; j += NBLK * 256)
        atomicAdd(&p.counts[dst_of(p.ei, j)], 1);
    __threadfence();
    grid.sync();

    // ================= P2: scan (bid 0) | nodeinit (bid 1..63) | w2t (bid 64..79) =================
    if (bid == 0) {
        int base = t * 63;
        int sum = 0;
        for (int i = 0; i < 63; ++i) {
            int idx = base + i;
            if (idx < NT) sum += p.counts[idx];
        }
        sm.scan[t] = sum;
        __syncthreads();
        for (int off = 1; off < 256; off <<= 1) {
            int v = (t >= off) ? sm.scan[t - off] : 0;
            __syncthreads();
            sm.scan[t] += v;
            __syncthreads();
        }
        int run = sm.scan[t] - sum;    // exclusive prefix of this chunk
        for (int i = 0; i < 63; ++i) {
            int idx = base + i;
            if (idx < NT) {
                int c = p.counts[idx];
                p.offs[idx] = run; p.cursor[idx] = run; run += c;
            }
        }
        if (t == 255) p.offs[NT] = sm.scan[255];
    } else if (bid < 64) {
        int n = (bid - 1) * 256 + t;
        if (n < NT) {
            float x0 = p.actions[n * 2 + 0];
            float x1v = p.actions[n * 2 + 1];
            float x2v = p.nf[n];
            float4_ xv = {x0, x1v, x2v, 0.f};
            *(float4_*)(p.x4 + (size_t)n * 4) = xv;
            #pragma unroll
            for (int h = 0; h < 8; ++h) {
                p.as1[n * 8 + h] = x0 * p.wa_s[h] + x1v * p.wa_s[8 + h] + x2v * p.wa_s[16 + h];
                p.ad1[n * 8 + h] = x0 * p.wa_d[h] + x1v * p.wa_d[8 + h] + x2v * p.wa_d[16 + h];
            }
        }
    } else if (bid < 80) {
        int k0 = (bid - 64) * 64;
        int c = t & 63, g = t >> 6;
        for (int r = g; r < 64; r += 4)
            sm.tile[r][c] = p.W2[(size_t)(k0 + r) * 64 + c];
        __syncthreads();
        for (int n = g; n < 64; n += 4)
            p.w2t[(size_t)n * 1024 + k0 + c] = f2h(sm.tile[c][n]);
    }
    __threadfence();
    grid.sync();

    // ================= P3: CSR fill =================
    for (int j = bid * 256 + t; j < ETOT; j += NBLK * 256) {
        int dv = dst_of(p.ei, j);
        int pos = atomicAdd(&p.cursor[dv], 1);
        p.esrc[pos] = src_of(p.ei, j);
    }
    __threadfence();
    grid.sync();

    // ================= P4: conv1 (16 nodes / logical block) =================
    {
        // per-thread W1/b1 slice in registers (channels 4t..4t+3), loaded once
        float4_ w0 = *(const float4_*)(p.W1 + t * 4);
        float4_ w1r = *(const float4_*)(p.W1 + F1 + t * 4);
        float4_ w2r = *(const float4_*)(p.W1 + 2 * F1 + t * 4);
        float4_ bb = *(const float4_*)(p.b1 + t * 4);
        int g = lane >> 4, lg = lane & 15, eslot = lg >> 3, h = lg & 7;
        int hh = t >> 5;
        for (int db = bid; db < NT / 16; db += NBLK) {
            int nd0 = wave * 4 + g;
            int d = db * 16 + nd0;
            int off = p.offs[d], end = p.offs[d + 1];
            float adv = p.ad1[d * 8 + h];
            float den = 0.f, s0 = 0.f, s1 = 0.f, s2 = 0.f;
            for (int e = off + eslot; e < end; e += 2) {
                int s = p.esrc[e];
                float ea = __expf(lrelu02(p.as1[s * 8 + h] + adv));
                float4_ xv = *(const float4_*)(p.x4 + (size_t)s * 4);
                den += ea; s0 += ea * xv.x; s1 += ea * xv.y; s2 += ea * xv.z;
            }
            den += __shfl_xor(den, 8, 64);
            s0  += __shfl_xor(s0, 8, 64);
            s1  += __shfl_xor(s1, 8, 64);
            s2  += __shfl_xor(s2, 8, 64);
            if (eslot == 0) {
                float inv = 1.f / den;
                sm.smb[nd0][h][0] = s0 * inv;
                sm.smb[nd0][h][1] = s1 * inv;
                sm.smb[nd0][h][2] = s2 * inv;
            }
            __syncthreads();
            uint2_* xr = (uint2_*)(p.x1h + (size_t)db * 16 * F1 + t * 4);
            #pragma unroll 4
            for (int nd = 0; nd < 16; ++nd) {
                float c0 = sm.smb[nd][hh][0], c1 = sm.smb[nd][hh][1], c2 = sm.smb[nd][hh][2];
                float v0 = c0 * w0.x + c1 * w1r.x + c2 * w2r.x + bb.x;
                float v1 = c0 * w0.y + c1 * w1r.y + c2 * w2r.y + bb.y;
                float v2 = c0 * w0.z + c1 * w1r.z + c2 * w2r.z + bb.z;
                float v3 = c0 * w0.w + c1 * w1r.w + c2 * w2r.w + bb.w;
                v0 = elu1(v0); v1 = elu1(v1); v2 = elu1(v2); v3 = elu1(v3);
                uint2_ pk;
                pk.x = (uint_t)f2h(v0) | ((uint_t)f2h(v1) << 16);
                pk.y = (uint_t)f2h(v2) | ((uint_t)f2h(v3) << 16);
                xr[(size_t)nd * (F1 / 4)] = pk;
            }
            __syncthreads();   // protect smb against next-iteration WAR
        }
    }
    __threadfence();
    grid.sync();

    // ================= P5: h2 = x1 @ W2 (fp16 MFMA) + a2s/a2d epilogue =================
    if (bid < NT / 64) {
        int row0 = bid * 64 + wave * 16;
        int col = lane & 15, kg = lane >> 4;
        const ushort_t* ap = p.x1h + (size_t)(row0 + col) * F1 + kg * 8;
        const ushort_t* bp = p.w2t + (size_t)col * F1 + kg * 8;
        float4_ acc[4] = {{0,0,0,0},{0,0,0,0},{0,0,0,0},{0,0,0,0}};
        #pragma unroll 4
        for (int ks = 0; ks < F1; ks += 32) {
            half8 a = *(const half8*)(ap + ks);
            #pragma unroll
            for (int t4 = 0; t4 < 4; ++t4) {
                half8 b = *(const half8*)(bp + (size_t)t4 * 16 * F1 + ks);
                acc[t4] = __builtin_amdgcn_mfma_f32_16x16x32_f16(a, b, acc[t4], 0, 0, 0);
            }
        }
        #pragma unroll
        for (int t4 = 0; t4 < 4; ++t4) {
            #pragma unroll
            for (int r = 0; r < 4; ++r)
                p.h2[(size_t)(row0 + kg * 4 + r) * EMB + t4 * 16 + col] = acc[t4][r];
        }
        float ps[4] = {0.f, 0.f, 0.f, 0.f}, pd[4] = {0.f, 0.f, 0.f, 0.f};
        #pragma unroll
        for (int t4 = 0; t4 < 4; ++t4) {
            float sw = p.as2w[t4 * 16 + col];
            float dw = p.ad2w[t4 * 16 + col];
            #pragma unroll
            for (int r = 0; r < 4; ++r) {
                ps[r] += acc[t4][r] * sw;
                pd[r] += acc[t4][r] * dw;
            }
        }
        #pragma unroll
        for (int st = 1; st < 16; st <<= 1) {
            #pragma unroll
            for (int r = 0; r < 4; ++r) {
                ps[r] += __shfl_xor(ps[r], st, 64);
                pd[r] += __shfl_xor(pd[r], st, 64);
            }
        }
        if (col == 0) {
            #pragma unroll
            for (int r = 0; r < 4; ++r) {
                p.a2s[row0 + kg * 4 + r] = ps[r];
                p.a2d[row0 + kg * 4 + r] = pd[r];
            }
        }
    }
    __threadfence();
    grid.sync();

    // ================= P6: conv2 (wave per node) -> x2t =================
    {
        int eg = lane >> 4, c4 = (lane & 15) * 4;
        for (int cb = bid; cb < NT / 4; cb += NBLK) {
            int d = cb * 4 + wave;
            int off = p.offs[d], end = p.offs[d + 1];
            float adv = p.a2d[d];
            float den = 0.f;
            float4_ acc = {0.f, 0.f, 0.f, 0.f};
            for (int e = off + eg; e < end; e += 4) {
                int s = p.esrc[e];
                float ea = __expf(lrelu02(p.a2s[s] + adv));
                float4_ hv = *(const float4_*)(p.h2 + (size_t)s * EMB + c4);
                den += ea;
                acc.x += ea * hv.x; acc.y += ea * hv.y; acc.z += ea * hv.z; acc.w += ea * hv.w;
            }
            #pragma unroll
            for (int st = 16; st < 64; st <<= 1) {
                den   += __shfl_xor(den, st, 64);
                acc.x += __shfl_xor(acc.x, st, 64);
                acc.y += __shfl_xor(acc.y, st, 64);
                acc.z += __shfl_xor(acc.z, st, 64);
                acc.w += __shfl_xor(acc.w, st, 64);
            }
            if (eg == 0) {
                float inv = 1.f / den;
                int n = d % NN, b = d / NN;
                #pragma unroll
                for (int q = 0; q < 4; ++q) {
                    float v = acc[q] * inv + p.b2[c4 + q];
                    p.x2t[(size_t)(n * EMB + c4 + q) * NB + b] = elu1(v);
                }
            }
        }
    }
    __threadfence();
    grid.sync();

    // ================= P7: mlp1 stage A (block bid -> y1part[bid]) =================
    {
        int j2 = lane * 2;
        float2_ acc[NB];
        #pragma unroll
        for (int b = 0; b < NB; ++b) acc[b] = (float2_){0.f, 0.f};
        for (int k = bid * 4 + wave; k < KTOT; k += NBLK * 4) {
            int kk = __builtin_amdgcn_readfirstlane(k);
            float2_ w = *(const float2_*)(p.mw1 + (size_t)kk * HID + j2);
            const float* xr = p.x2t + (size_t)kk * NB;
            #pragma unroll
            for (int b = 0; b < NB; ++b) {
                float xv = xr[b];
                acc[b].x += xv * w.x;
                acc[b].y += xv * w.y;
            }
        }
        __syncthreads();   // sm union transition (smb -> red)
        for (int w = 0; w < 4; ++w) {
            if (wave == w) {
                #pragma unroll
                for (int b = 0; b < NB; ++b) {
                    if (w == 0) {
                        sm.red[b * HID + j2]     = acc[b].x;
                        sm.red[b * HID + j2 + 1] = acc[b].y;
                    } else {
                        sm.red[b * HID + j2]     += acc[b].x;
                        sm.red[b * HID + j2 + 1] += acc[b].y;
                    }
                }
            }
            __syncthreads();
        }
        float* yp = p.y1part + (size_t)bid * (NB * HID);
        for (int idx = t; idx < NB * HID; idx += 256)
            yp[idx] = sm.red[idx];
    }
    __threadfence();
    grid.sync();

    // ================= P8: mlp1 stage B (reduce 512 partials) =================
    if (bid < 64) {
        int pc = bid >> 3, oc = bid & 7;
        int idx = oc * 256 + t;
        float s = 0.f;
        #pragma unroll 4
        for (int pp = pc * 64; pp < pc * 64 + 64; ++pp)
            s += p.y1part[(size_t)pp * (NB * HID) + idx];
        atomicAdd(&p.y1sum[idx], s);
    }
    __threadfence();
    grid.sync();

    // ================= P9: mlp2 (single block) =================
    if (bid == 0) {
        for (int idx = t; idx < NB * HID; idx += 256)
            sm.red[idx] = fmaxf(p.y1sum[idx] + p.mb1[idx & 127], 0.f);
        __syncthreads();
        #pragma unroll
        for (int i = 0; i < 8; ++i) {
            int o = t + i * 256;
            int b = o >> 7, j = o & 127;
            float acc = p.mb2[j];
            for (int k = 0; k < HID; ++k) acc += sm.red[b * HID + k] * p.mw2[k * HID + j];
            p.y2[o] = fmaxf(acc, 0.f);
        }
    }
    __threadfence();
    grid.sync();

    // ================= P10: out = sigmoid(y2 @ out_w + out_b) =================
    if (bid < 4) {
        int n = bid * 256 + t;
        if (n < NN) {
            float acc[NB];
            #pragma unroll
            for (int b = 0; b < NB; ++b) acc[b] = 0.f;
            for (int jj = 0; jj < HID; ++jj) {
                float w = p.ow[jj * NN + n];
                #pragma unroll
                for (int b = 0; b < NB; ++b) acc[b] += p.y2[b * HID + jj] * w;
            }
            float obv = p.ob[n];
            #pragma unroll
            for (int b = 0; b < NB; ++b)
                p.out[b * NN + n] = 1.f / (1.f + __expf(-(acc[b] + obv)));
        }
    }
}

extern "C" void kernel_launch(void* const* d_in, const int* in_sizes, int n_in,
                              void* d_out, int out_size, void* d_ws, size_t ws_size,
                              hipStream_t stream) {
    GParams g;
    g.actions = (const float*)d_in[0];
    g.nf      = (const float*)d_in[1];
    g.ei      = (const int*)d_in[2];
    g.W1      = (const float*)d_in[3];
    g.as1w    = (const float*)d_in[4];
    g.ad1w    = (const float*)d_in[5];
    g.b1      = (const float*)d_in[6];
    g.W2      = (const float*)d_in[7];
    g.as2w    = (const float*)d_in[8];
    g.ad2w    = (const float*)d_in[9];
    g.b2      = (const float*)d_in[10];
    g.mw1     = (const float*)d_in[11];
    g.mb1     = (const float*)d_in[12];
    g.mw2     = (const float*)d_in[13];
    g.mb2     = (const float*)d_in[14];
    g.ow      = (const float*)d_in[15];
    g.ob      = (const float*)d_in[16];
    g.out     = (float*)d_out;

    // workspace carve (all segments 16B-aligned)
    float* f = (float*)d_ws;
    g.x4    = f;  f += (size_t)NT * 4;
    g.h2    = f;  f += (size_t)NT * EMB;
    g.x2t   = f;  f += (size_t)NT * EMB;
    g.as1   = f;  f += NT * 8;
    g.ad1   = f;  f += NT * 8;
    g.a2s   = f;  f += NT;
    g.a2d   = f;  f += NT;
    g.wa_s  = f;  f += 32;
    g.wa_d  = f;  f += 32;
    g.y1part= f;  f += (size_t)NBLK * NB * HID;
    g.y1sum = f;  f += NB * HID;
    g.y2    = f;  f += NB * HID;
    g.x1h   = (ushort_t*)f;
    g.w2t   = g.x1h + (size_t)NT * F1;
    int* ip = (int*)(g.w2t + (size_t)EMB * F1);
    g.counts = ip; ip += NT;
    g.offs   = ip; ip += NT + 1;
    g.cursor = ip; ip += NT;
    g.esrc   = ip; ip += ETOT;

    void* args[] = {(void*)&g};
    hipLaunchCooperativeKernel((const void*)k_mega, dim3(NBLK), dim3(256), args, 0, stream);
}

// Round 7
// 312.001 us; speedup vs baseline: 4.3237x; 4.3237x over previous
//
#include <hip/hip_runtime.h>
#include <math.h>

#define NB 16
#define NN 1000
#define NT 16000          // NB*NN total nodes
#define NE 16000          // edges per graph
#define EBASE 256000      // NB*NE
#define ETOT 272000       // EBASE + NT self loops
#define F1 1024           // H1*C1
#define EMB 64
#define HID 128
#define KTOT 64000        // N*EMB mlp1 reduction length
#define MLP1B 512         // mlp1 stage-A partial count

typedef unsigned short ushort_t;
typedef unsigned int uint_t;
typedef __attribute__((ext_vector_type(8))) _Float16 half8;
typedef __attribute__((ext_vector_type(4))) float float4_;
typedef __attribute__((ext_vector_type(2))) float float2_;
typedef __attribute__((ext_vector_type(2))) uint_t uint2_;

// ---- scrambled edge mapping (faithful to reference row-major reshape) ----
__device__ __forceinline__ int src_of(const int* ei, int j) {
    if (j < EBASE) return ei[j] + (j / 32000) * 1000;
    return j - EBASE;
}
__device__ __forceinline__ int dst_of(const int* ei, int j) {
    if (j < EBASE) return ei[EBASE + j] + (8 + j / 32000) * 1000;
    return j - EBASE;
}

__device__ __forceinline__ float lrelu02(float r) { return r >= 0.f ? r : 0.2f * r; }
__device__ __forceinline__ float elu1(float v)    { return v > 0.f ? v : expm1f(v); }
__device__ __forceinline__ ushort_t f2h(float f) {
    _Float16 h = (_Float16)f;           // v_cvt_f16_f32, RTE
    union { _Float16 h; ushort_t u; } c; c.h = h; return c.u;
}

// ==== k_prep: {edge count | wa precontract | W2 -> fragment-major fp16 w2f} ====
// w2f chunk q = (t4*32 + kstep)*64 + lane holds 8 fp16: W2[k][n],
//   k = kstep*32 + (lane>>4)*8 + j,  n = t4*16 + (lane&15)   (B-frag coalesced)
__global__ __launch_bounds__(256) void k_prep(
    const int* __restrict__ ei, int* __restrict__ counts,
    const float* __restrict__ W1, const float* __restrict__ as1w, const float* __restrict__ ad1w,
    const float* __restrict__ W2, float* __restrict__ wa_s, float* __restrict__ wa_d,
    ushort_t* __restrict__ w2f) {
    __shared__ float tile[64][65];
    int blk = blockIdx.x, t = threadIdx.x;
    if (blk < 1063) {                       // CSR histogram
        int j = blk * 256 + t;
        if (j < ETOT) atomicAdd(&counts[dst_of(ei, j)], 1);
    } else if (blk == 1063) {               // wa[3][8] precontract for conv1 logits
        if (t < 24) {
            int k = t / 8, h = t % 8;
            float ss = 0.f, dd = 0.f;
            for (int c = 0; c < 128; ++c) {
                float w = W1[k * F1 + h * 128 + c];
                ss += w * as1w[h * 128 + c];
                dd += w * ad1w[h * 128 + c];
            }
            wa_s[k * 8 + h] = ss; wa_d[k * 8 + h] = dd;
        }
    } else {                                // W2 rows k0..k0+63 -> w2f
        int k0 = (blk - 1064) * 64;
        int c = t & 63, g = t >> 6;
        for (int r = g; r < 64; r += 4)
            tile[r][c] = W2[(size_t)(k0 + r) * 64 + c];
        __syncthreads();
        for (int q = t; q < 512; q += 256) {
            int t4 = q >> 7, ksl = (q >> 6) & 1, l8 = q & 63;
            int kg = l8 >> 4, mrow = l8 & 15;
            int n = t4 * 16 + mrow;
            int kloc = ksl * 32 + kg * 8;
            size_t base = (((size_t)t4 * 32 + (k0 >> 5) + ksl) * 64 + l8) * 8;
            #pragma unroll
            for (int j = 0; j < 8; ++j)
                w2f[base + j] = f2h(tile[kloc + j][n]);
        }
    }
}

// ==== k_prep2: {CSR scan (block 0) | nodeinit (blocks 1..16)} ====
__global__ __launch_bounds__(1024) void k_prep2(
    const float* __restrict__ actions, const float* __restrict__ nf,
    const float* __restrict__ wa_s, const float* __restrict__ wa_d,
    float* __restrict__ x4, float* __restrict__ as1, float* __restrict__ ad1,
    const int* __restrict__ counts, int* __restrict__ offs, int* __restrict__ cursor) {
    __shared__ int lds[1024];
    int t = threadIdx.x;
    if (blockIdx.x == 0) {
        int base = t * 16;
        int local[16];
        int mysum = 0;
        #pragma unroll
        for (int i = 0; i < 16; ++i) {
            int idx = base + i;
            int c = (idx < NT) ? counts[idx] : 0;
            local[i] = c; mysum += c;
        }
        lds[t] = mysum;
        __syncthreads();
        for (int off = 1; off < 1024; off <<= 1) {
            int v = (t >= off) ? lds[t - off] : 0;
            __syncthreads();
            lds[t] += v;
            __syncthreads();
        }
        int run = lds[t] - mysum;
        #pragma unroll
        for (int i = 0; i < 16; ++i) {
            int idx = base + i;
            if (idx < NT) { offs[idx] = run; cursor[idx] = run; run += local[i]; }
        }
        if (t == 1023) offs[NT] = lds[1023];
    } else {
        int n = (blockIdx.x - 1) * 1000 + t;
        if (t < 1000) {
            float x0 = actions[n * 2 + 0];
            float x1v = actions[n * 2 + 1];
            float x2v = nf[n];
            float4_ xv = {x0, x1v, x2v, 0.f};
            *(float4_*)(x4 + (size_t)n * 4) = xv;
            #pragma unroll
            for (int h = 0; h < 8; ++h) {
                as1[n * 8 + h] = x0 * wa_s[h] + x1v * wa_s[8 + h] + x2v * wa_s[16 + h];
                ad1[n * 8 + h] = x0 * wa_d[h] + x1v * wa_d[8 + h] + x2v * wa_d[16 + h];
            }
        }
    }
}

// ==== k_fill: CSR fill ====
__global__ void k_fill(const int* __restrict__ ei, int* __restrict__ cursor, int* __restrict__ esrc) {
    int j = blockIdx.x * blockDim.x + threadIdx.x;
    if (j >= ETOT) return;
    int dv = dst_of(ei, j);
    int pos = atomicAdd(&cursor[dv], 1);
    esrc[pos] = src_of(ei, j);
}

// ==== k_conv1h2: fused conv1 + h2-GEMM (x1 tile lives only in LDS) ====
// Block = 16 nodes. A: edge softmax -> smb. B: x1 channels -> LDS fp16 tile.
// C: per-wave MFMA (wave = 16-col output slice) + a2s/a2d epilogue.
__global__ __launch_bounds__(256) void k_conv1h2(
    const int* __restrict__ offs, const int* __restrict__ esrc, const float* __restrict__ x4,
    const float* __restrict__ as1, const float* __restrict__ ad1,
    const float* __restrict__ W1, const float* __restrict__ b1,
    const ushort_t* __restrict__ w2f,
    const float* __restrict__ as2w, const float* __restrict__ ad2w,
    float* __restrict__ h2, float* __restrict__ a2s, float* __restrict__ a2d) {
    __shared__ ushort_t x1t[16][1032];   // padded: row stride 2064 B -> 2-way-bank (free)
    __shared__ float smb[16][8][3];
    __shared__ float a2p[4][16][2];
    int t = threadIdx.x, wave = t >> 6, lane = t & 63;

    // W1/b1 slice in registers: channels 4t..4t+3 (loaded once, L2-hot)
    float4_ w0 = *(const float4_*)(W1 + t * 4);
    float4_ w1r = *(const float4_*)(W1 + F1 + t * 4);
    float4_ w2r = *(const float4_*)(W1 + 2 * F1 + t * 4);
    float4_ bb = *(const float4_*)(b1 + t * 4);

    // ---- phase A: edge softmax (4 nodes/wave, 16 lanes/node) ----
    int g = lane >> 4, lg = lane & 15, eslot = lg >> 3, h = lg & 7;
    int nd0 = wave * 4 + g;
    int d = blockIdx.x * 16 + nd0;
    int off = offs[d], end = offs[d + 1];
    float adv = ad1[d * 8 + h];
    float den = 0.f, s0 = 0.f, s1 = 0.f, s2 = 0.f;
    for (int e = off + eslot; e < end; e += 2) {
        int s = esrc[e];
        float ea = __expf(lrelu02(as1[s * 8 + h] + adv));
        float4_ xv = *(const float4_*)(x4 + (size_t)s * 4);
        den += ea; s0 += ea * xv.x; s1 += ea * xv.y; s2 += ea * xv.z;
    }
    den += __shfl_xor(den, 8, 64);
    s0  += __shfl_xor(s0, 8, 64);
    s1  += __shfl_xor(s1, 8, 64);
    s2  += __shfl_xor(s2, 8, 64);
    if (eslot == 0) {
        float inv = 1.f / den;
        smb[nd0][h][0] = s0 * inv;
        smb[nd0][h][1] = s1 * inv;
        smb[nd0][h][2] = s2 * inv;
    }
    __syncthreads();

    // ---- phase B: x1 = elu(xs @ W1 + b1) -> LDS fp16 ----
    int hh = t >> 5;
    #pragma unroll 4
    for (int nd = 0; nd < 16; ++nd) {
        float c0 = smb[nd][hh][0], c1 = smb[nd][hh][1], c2 = smb[nd][hh][2];
        float v0 = c0 * w0.x + c1 * w1r.x + c2 * w2r.x + bb.x;
        float v1 = c0 * w0.y + c1 * w1r.y + c2 * w2r.y + bb.y;
        float v2 = c0 * w0.z + c1 * w1r.z + c2 * w2r.z + bb.z;
        float v3 = c0 * w0.w + c1 * w1r.w + c2 * w2r.w + bb.w;
        v0 = elu1(v0); v1 = elu1(v1); v2 = elu1(v2); v3 = elu1(v3);
        uint2_ pk;
        pk.x = (uint_t)f2h(v0) | ((uint_t)f2h(v1) << 16);
        pk.y = (uint_t)f2h(v2) | ((uint_t)f2h(v3) << 16);
        *(uint2_*)(&x1t[nd][t * 4]) = pk;
    }
    __syncthreads();

    // ---- phase C: 16x64 = x1t(16x1024) @ W2, wave owns out-cols wave*16..+15 ----
    int mrow = lane & 15, kg = lane >> 4;
    const ushort_t* bp = w2f + ((size_t)wave * 32 * 64 + lane) * 8;
    float4_ acc = {0.f, 0.f, 0.f, 0.f};
    #pragma unroll 8
    for (int ks = 0; ks < 32; ++ks) {
        half8 a = *(const half8*)(&x1t[mrow][kg * 8 + ks * 32]);
        half8 b = *(const half8*)(bp + (size_t)ks * 512);
        acc = __builtin_amdgcn_mfma_f32_16x16x32_f16(a, b, acc, 0, 0, 0);
    }
    int row0 = blockIdx.x * 16;
    #pragma unroll
    for (int r = 0; r < 4; ++r)
        h2[(size_t)(row0 + kg * 4 + r) * EMB + wave * 16 + mrow] = acc[r];

    // a2s/a2d = h2 . att2 (fused epilogue)
    float sw = as2w[wave * 16 + mrow], dw = ad2w[wave * 16 + mrow];
    float ps[4], pd[4];
    #pragma unroll
    for (int r = 0; r < 4; ++r) { ps[r] = acc[r] * sw; pd[r] = acc[r] * dw; }
    #pragma unroll
    for (int st = 1; st < 16; st <<= 1) {
        #pragma unroll
        for (int r = 0; r < 4; ++r) {
            ps[r] += __shfl_xor(ps[r], st, 64);
            pd[r] += __shfl_xor(pd[r], st, 64);
        }
    }
    if (mrow == 0) {
        #pragma unroll
        for (int r = 0; r < 4; ++r) {
            a2p[wave][kg * 4 + r][0] = ps[r];
            a2p[wave][kg * 4 + r][1] = pd[r];
        }
    }
    __syncthreads();
    if (t < 16) {
        float ss = a2p[0][t][0] + a2p[1][t][0] + a2p[2][t][0] + a2p[3][t][0];
        float dd = a2p[0][t][1] + a2p[1][t][1] + a2p[2][t][1] + a2p[3][t][1];
        a2s[row0 + t] = ss; a2d[row0 + t] = dd;
    }
}

// ==== k_conv2: fused softmax+message; wave per node; COALESCED x2[d][c] write ====
__global__ __launch_bounds__(256) void k_conv2(
    const int* __restrict__ offs, const int* __restrict__ esrc, const float* __restrict__ h2,
    const float* __restrict__ a2s, const float* __restrict__ a2d, const float* __restrict__ b2,
    float* __restrict__ x2) {
    int t = threadIdx.x;
    int wave = t >> 6, lane = t & 63;
    int d = blockIdx.x * 4 + wave;
    int off = offs[d], end = offs[d + 1];
    float adv = a2d[d];
    int eg = lane >> 4, c4 = (lane & 15) * 4;

    float den = 0.f;
    float4_ acc = {0.f, 0.f, 0.f, 0.f};
    for (int e = off + eg; e < end; e += 4) {
        int s = esrc[e];
        float ea = __expf(lrelu02(a2s[s] + adv));
        float4_ hv = *(const float4_*)(h2 + (size_t)s * EMB + c4);
        den += ea;
        acc.x += ea * hv.x; acc.y += ea * hv.y; acc.z += ea * hv.z; acc.w += ea * hv.w;
    }
    #pragma unroll
    for (int st = 16; st < 64; st <<= 1) {
        den   += __shfl_xor(den, st, 64);
        acc.x += __shfl_xor(acc.x, st, 64);
        acc.y += __shfl_xor(acc.y, st, 64);
        acc.z += __shfl_xor(acc.z, st, 64);
        acc.w += __shfl_xor(acc.w, st, 64);
    }
    if (eg == 0) {
        float inv = 1.f / den;
        float4_ o;
        o.x = elu1(acc.x * inv + b2[c4 + 0]);
        o.y = elu1(acc.y * inv + b2[c4 + 1]);
        o.z = elu1(acc.z * inv + b2[c4 + 2]);
        o.w = elu1(acc.w * inv + b2[c4 + 3]);
        *(float4_*)(x2 + (size_t)d * EMB + c4) = o;   // 256 B contiguous per node
    }
}

// ==== k_mlp1 stage A: x2 natural layout is [b][k]; k uniform per wave ====
__global__ __launch_bounds__(256) void k_mlp1(const float* __restrict__ x2,
                                              const float* __restrict__ w1,
                                              float* __restrict__ y1part) {
    __shared__ float red[NB * HID];
    int t = threadIdx.x;
    int wave = t >> 6, lane = t & 63;
    int j2 = lane * 2;
    float2_ acc[NB];
    #pragma unroll
    for (int b = 0; b < NB; ++b) acc[b] = (float2_){0.f, 0.f};

    for (int k = blockIdx.x * 4 + wave; k < KTOT; k += MLP1B * 4) {
        int kk = __builtin_amdgcn_readfirstlane(k);
        float2_ w = *(const float2_*)(w1 + (size_t)kk * HID + j2);
        const float* xr = x2 + kk;            // x2[b*64000 + kk] -> wave-uniform s_loads
        #pragma unroll
        for (int b = 0; b < NB; ++b) {
            float xv = xr[(size_t)b * KTOT];
            acc[b].x += xv * w.x;
            acc[b].y += xv * w.y;
        }
    }
    for (int w = 0; w < 4; ++w) {
        if (wave == w) {
            #pragma unroll
            for (int b = 0; b < NB; ++b) {
                if (w == 0) {
                    red[b * HID + j2]     = acc[b].x;
                    red[b * HID + j2 + 1] = acc[b].y;
                } else {
                    red[b * HID + j2]     += acc[b].x;
                    red[b * HID + j2 + 1] += acc[b].y;
                }
            }
        }
        __syncthreads();
    }
    float* yp = y1part + (size_t)blockIdx.x * (NB * HID);
    for (int idx = t; idx < NB * HID; idx += 256)
        yp[idx] = red[idx];
}

// ==== k_mlp1b: reduce 512 partials -> y1sum (direct write, no atomics) ====
__global__ __launch_bounds__(256) void k_mlp1b(const float* __restrict__ y1part,
                                               float* __restrict__ y1sum) {
    int idx = blockIdx.x * 256 + threadIdx.x;   // 8 blocks x 256 = 2048
    float s = 0.f;
    #pragma unroll 8
    for (int p = 0; p < MLP1B; ++p)
        s += y1part[(size_t)p * (NB * HID) + idx];
    y1sum[idx] = s;
}

// ==== k_mlp2out: relu(y1+b1) -> y2 = relu(y1@w2+b2) -> out = sigmoid(y2@ow+ob) ====
__global__ __launch_bounds__(256) void k_mlp2out(
    const float* __restrict__ y1sum, const float* __restrict__ mb1,
    const float* __restrict__ mw2, const float* __restrict__ mb2,
    const float* __restrict__ ow, const float* __restrict__ ob,
    float* __restrict__ out) {
    __shared__ float y1[NB * HID];
    __shared__ float y2s[NB * HID];
    int t = threadIdx.x;
    for (int idx = t; idx < NB * HID; idx += 256)
        y1[idx] = fmaxf(y1sum[idx] + mb1[idx & 127], 0.f);
    __syncthreads();
    #pragma unroll
    for (int i = 0; i < 8; ++i) {
        int o = t + i * 256;
        int b = o >> 7, j = o & 127;
        float acc = mb2[j];
        for (int k = 0; k < HID; ++k) acc += y1[b * HID + k] * mw2[k * HID + j];
        y2s[o] = fmaxf(acc, 0.f);
    }
    __syncthreads();
    for (int n = t; n < NN; n += 256) {
        float acc[NB];
        #pragma unroll
        for (int b = 0; b < NB; ++b) acc[b] = 0.f;
        for (int j = 0; j < HID; ++j) {
            float w = ow[j * NN + n];
            #pragma unroll
            for (int b = 0; b < NB; ++b) acc[b] += y2s[b * HID + j] * w;
        }
        float obv = ob[n];
        #pragma unroll
        for (int b = 0; b < NB; ++b)
            out[b * NN + n] = 1.f / (1.f + __expf(-(acc[b] + obv)));
    }
}

extern "C" void kernel_launch(void* const* d_in, const int* in_sizes, int n_in,
                              void* d_out, int out_size, void* d_ws, size_t ws_size,
                              hipStream_t stream) {
    const float* actions = (const float*)d_in[0];
    const float* nf      = (const float*)d_in[1];
    const int*   ei      = (const int*)d_in[2];
    const float* W1      = (const float*)d_in[3];
    const float* as1w    = (const float*)d_in[4];
    const float* ad1w    = (const float*)d_in[5];
    const float* b1      = (const float*)d_in[6];
    const float* W2      = (const float*)d_in[7];
    const float* as2w    = (const float*)d_in[8];
    const float* ad2w    = (const float*)d_in[9];
    const float* b2      = (const float*)d_in[10];
    const float* mw1     = (const float*)d_in[11];
    const float* mb1     = (const float*)d_in[12];
    const float* mw2     = (const float*)d_in[13];
    const float* mb2     = (const float*)d_in[14];
    const float* ow      = (const float*)d_in[15];
    const float* ob      = (const float*)d_in[16];
    float* out = (float*)d_out;

    // workspace carve (all segments 16B-aligned; no x1h anymore)
    float* f = (float*)d_ws;
    float* x4    = f;  f += (size_t)NT * 4;
    float* h2    = f;  f += (size_t)NT * EMB;
    float* x2    = f;  f += (size_t)NT * EMB;
    float* as1   = f;  f += NT * 8;
    float* ad1   = f;  f += NT * 8;
    float* a2s   = f;  f += NT;
    float* a2d   = f;  f += NT;
    float* wa_s  = f;  f += 32;
    float* wa_d  = f;  f += 32;
    float* y1part= f;  f += (size_t)MLP1B * NB * HID;
    float* y1sum = f;  f += NB * HID;
    ushort_t* w2f = (ushort_t*)f;                 // 4*32*64*8 = 65536 fp16
    int* ip = (int*)(w2f + 65536);
    int* counts = ip; ip += NT;
    int* offs   = ip; ip += NT + 1;
    int* cursor = ip; ip += NT;
    int* esrc   = ip; ip += ETOT;

    hipMemsetAsync(counts, 0, NT * sizeof(int), stream);

    k_prep<<<1080, 256, 0, stream>>>(ei, counts, W1, as1w, ad1w, W2, wa_s, wa_d, w2f);
    k_prep2<<<17, 1024, 0, stream>>>(actions, nf, wa_s, wa_d, x4, as1, ad1, counts, offs, cursor);
    k_fill<<<(ETOT + 255) / 256, 256, 0, stream>>>(ei, cursor, esrc);
    k_conv1h2<<<NT / 16, 256, 0, stream>>>(offs, esrc, x4, as1, ad1, W1, b1, w2f,
                                           as2w, ad2w, h2, a2s, a2d);
    k_conv2<<<NT / 4, 256, 0, stream>>>(offs, esrc, h2, a2s, a2d, b2, x2);
    k_mlp1<<<MLP1B, 256, 0, stream>>>(x2, mw1, y1part);
    k_mlp1b<<<8, 256, 0, stream>>>(y1part, y1sum);
    k_mlp2out<<<1, 256, 0, stream>>>(y1sum, mb1, mw2, mb2, ow, ob, out);
}

// Round 8
// 297.556 us; speedup vs baseline: 4.5336x; 1.0485x over previous
//
#include <hip/hip_runtime.h>
#include <math.h>

#define NB 16
#define NN 1000
#define NT 16000          // NB*NN total nodes
#define NE 16000          // edges per graph
#define EBASE 256000      // NB*NE
#define ETOT 272000       // EBASE + NT self loops
#define F1 1024           // H1*C1
#define EMB 64
#define HID 128
#define KTOT 64000        // N*EMB mlp1 reduction length
#define MLP1B 128         // mlp1 stage-A partial count
#define CAP 96            // per-node edge slot capacity (max degree ~54 at z=3.9)

typedef unsigned short ushort_t;
typedef unsigned int uint_t;
typedef __attribute__((ext_vector_type(8))) _Float16 half8;
typedef __attribute__((ext_vector_type(4))) float float4_;
typedef __attribute__((ext_vector_type(2))) float float2_;
typedef __attribute__((ext_vector_type(2))) uint_t uint2_;

// ---- scrambled edge mapping (faithful to reference row-major reshape) ----
__device__ __forceinline__ int src_of(const int* ei, int j) {
    if (j < EBASE) return ei[j] + (j / 32000) * 1000;
    return j - EBASE;
}
__device__ __forceinline__ int dst_of(const int* ei, int j) {
    if (j < EBASE) return ei[EBASE + j] + (8 + j / 32000) * 1000;
    return j - EBASE;
}

__device__ __forceinline__ float lrelu02(float r) { return r >= 0.f ? r : 0.2f * r; }
__device__ __forceinline__ float elu1(float v)    { return v > 0.f ? v : expm1f(v); }
__device__ __forceinline__ ushort_t f2h(float f) {
    _Float16 h = (_Float16)f;           // v_cvt_f16_f32, RTE
    union { _Float16 h; ushort_t u; } c; c.h = h; return c.u;
}

// ==== k_prep0 (32 blocks x 1024): zero cnt | nodeinit (bid 0..15, wa redundant)
//      | W2 -> fragment-major fp16 w2f (bid 16..31) ====
__global__ __launch_bounds__(1024) void k_prep0(
    const float* __restrict__ actions, const float* __restrict__ nf,
    const float* __restrict__ W1, const float* __restrict__ as1w, const float* __restrict__ ad1w,
    const float* __restrict__ W2,
    float* __restrict__ x4, float* __restrict__ as1, float* __restrict__ ad1,
    ushort_t* __restrict__ w2f, int* __restrict__ cnt) {
    __shared__ float tile[64][65];
    __shared__ float was[24], wad[24];
    int bid = blockIdx.x, t = threadIdx.x;

    // zero edge counters (stream-ordered before k_fillslots)
    int zi = bid * 1024 + t;
    if (zi < NT) cnt[zi] = 0;

    if (bid < 16) {
        // wa[3][8] precontract, redundant per block
        if (t < 24) {
            int k = t / 8, h = t % 8;
            float ss = 0.f, dd = 0.f;
            for (int c = 0; c < 128; ++c) {
                float w = W1[k * F1 + h * 128 + c];
                ss += w * as1w[h * 128 + c];
                dd += w * ad1w[h * 128 + c];
            }
            was[t] = ss; wad[t] = dd;
        }
        __syncthreads();
        int n = bid * 1000 + t;
        if (t < 1000) {
            float x0 = actions[n * 2 + 0];
            float x1v = actions[n * 2 + 1];
            float x2v = nf[n];
            float4_ xv = {x0, x1v, x2v, 0.f};
            *(float4_*)(x4 + (size_t)n * 4) = xv;
            #pragma unroll
            for (int h = 0; h < 8; ++h) {
                as1[n * 8 + h] = x0 * was[h] + x1v * was[8 + h] + x2v * was[16 + h];
                ad1[n * 8 + h] = x0 * wad[h] + x1v * wad[8 + h] + x2v * wad[16 + h];
            }
        }
    } else {
        // W2 rows k0..k0+63 -> w2f fragment-major (layout identical to r7, verified)
        int k0 = (bid - 16) * 64;
        int c = t & 63, g = t >> 6;       // g in 0..15
        for (int r = g; r < 64; r += 16)
            tile[r][c] = W2[(size_t)(k0 + r) * 64 + c];
        __syncthreads();
        if (t < 512) {
            int q = t;
            int t4 = q >> 7, ksl = (q >> 6) & 1, l8 = q & 63;
            int kg = l8 >> 4, mrow = l8 & 15;
            int n = t4 * 16 + mrow;
            int kloc = ksl * 32 + kg * 8;
            size_t base = (((size_t)t4 * 32 + (k0 >> 5) + ksl) * 64 + l8) * 8;
            #pragma unroll
            for (int j = 0; j < 8; ++j)
                w2f[base + j] = f2h(tile[kloc + j][n]);
        }
    }
}

// ==== k_fillslots: single-pass edge bucketing (atomic slot per dst node) ====
__global__ void k_fillslots(const int* __restrict__ ei, int* __restrict__ cnt,
                            int* __restrict__ esrc) {
    int j = blockIdx.x * blockDim.x + threadIdx.x;
    if (j >= ETOT) return;
    int dv = dst_of(ei, j);
    int slot = atomicAdd(&cnt[dv], 1);
    if (slot < CAP) esrc[(size_t)dv * CAP + slot] = src_of(ei, j);
}

// ==== k_conv1h2: fused conv1 + h2-GEMM (x1 tile lives only in LDS) ====
__global__ __launch_bounds__(256) void k_conv1h2(
    const int* __restrict__ cnt, const int* __restrict__ esrc, const float* __restrict__ x4,
    const float* __restrict__ as1, const float* __restrict__ ad1,
    const float* __restrict__ W1, const float* __restrict__ b1,
    const ushort_t* __restrict__ w2f,
    const float* __restrict__ as2w, const float* __restrict__ ad2w,
    float* __restrict__ h2, float* __restrict__ a2s, float* __restrict__ a2d) {
    __shared__ ushort_t x1t[16][1032];   // padded: row stride 2064 B -> 2-way-bank (free)
    __shared__ float smb[16][8][3];
    __shared__ float a2p[4][16][2];
    int t = threadIdx.x, wave = t >> 6, lane = t & 63;

    // W1/b1 slice in registers: channels 4t..4t+3 (loaded once, L2-hot)
    float4_ w0 = *(const float4_*)(W1 + t * 4);
    float4_ w1r = *(const float4_*)(W1 + F1 + t * 4);
    float4_ w2r = *(const float4_*)(W1 + 2 * F1 + t * 4);
    float4_ bb = *(const float4_*)(b1 + t * 4);

    // ---- phase A: edge softmax (4 nodes/wave, 16 lanes/node) ----
    int g = lane >> 4, lg = lane & 15, eslot = lg >> 3, h = lg & 7;
    int nd0 = wave * 4 + g;
    int d = blockIdx.x * 16 + nd0;
    int cn = cnt[d];
    const int* ep = esrc + (size_t)d * CAP;
    float adv = ad1[d * 8 + h];
    float den = 0.f, s0 = 0.f, s1 = 0.f, s2 = 0.f;
    for (int e = eslot; e < cn; e += 2) {
        int s = ep[e];
        float ea = __expf(lrelu02(as1[s * 8 + h] + adv));
        float4_ xv = *(const float4_*)(x4 + (size_t)s * 4);
        den += ea; s0 += ea * xv.x; s1 += ea * xv.y; s2 += ea * xv.z;
    }
    den += __shfl_xor(den, 8, 64);
    s0  += __shfl_xor(s0, 8, 64);
    s1  += __shfl_xor(s1, 8, 64);
    s2  += __shfl_xor(s2, 8, 64);
    if (eslot == 0) {
        float inv = 1.f / den;
        smb[nd0][h][0] = s0 * inv;
        smb[nd0][h][1] = s1 * inv;
        smb[nd0][h][2] = s2 * inv;
    }
    __syncthreads();

    // ---- phase B: x1 = elu(xs @ W1 + b1) -> LDS fp16 ----
    int hh = t >> 5;
    #pragma unroll 4
    for (int nd = 0; nd < 16; ++nd) {
        float c0 = smb[nd][hh][0], c1 = smb[nd][hh][1], c2 = smb[nd][hh][2];
        float v0 = c0 * w0.x + c1 * w1r.x + c2 * w2r.x + bb.x;
        float v1 = c0 * w0.y + c1 * w1r.y + c2 * w2r.y + bb.y;
        float v2 = c0 * w0.z + c1 * w1r.z + c2 * w2r.z + bb.z;
        float v3 = c0 * w0.w + c1 * w1r.w + c2 * w2r.w + bb.w;
        v0 = elu1(v0); v1 = elu1(v1); v2 = elu1(v2); v3 = elu1(v3);
        uint2_ pk;
        pk.x = (uint_t)f2h(v0) | ((uint_t)f2h(v1) << 16);
        pk.y = (uint_t)f2h(v2) | ((uint_t)f2h(v3) << 16);
        *(uint2_*)(&x1t[nd][t * 4]) = pk;
    }
    __syncthreads();

    // ---- phase C: 16x64 = x1t(16x1024) @ W2, wave owns out-cols wave*16..+15 ----
    int mrow = lane & 15, kg = lane >> 4;
    const ushort_t* bp = w2f + ((size_t)wave * 32 * 64 + lane) * 8;
    float4_ acc = {0.f, 0.f, 0.f, 0.f};
    #pragma unroll 8
    for (int ks = 0; ks < 32; ++ks) {
        half8 a = *(const half8*)(&x1t[mrow][kg * 8 + ks * 32]);
        half8 b = *(const half8*)(bp + (size_t)ks * 512);
        acc = __builtin_amdgcn_mfma_f32_16x16x32_f16(a, b, acc, 0, 0, 0);
    }
    int row0 = blockIdx.x * 16;
    #pragma unroll
    for (int r = 0; r < 4; ++r)
        h2[(size_t)(row0 + kg * 4 + r) * EMB + wave * 16 + mrow] = acc[r];

    // a2s/a2d = h2 . att2 (fused epilogue)
    float sw = as2w[wave * 16 + mrow], dw = ad2w[wave * 16 + mrow];
    float ps[4], pd[4];
    #pragma unroll
    for (int r = 0; r < 4; ++r) { ps[r] = acc[r] * sw; pd[r] = acc[r] * dw; }
    #pragma unroll
    for (int st = 1; st < 16; st <<= 1) {
        #pragma unroll
        for (int r = 0; r < 4; ++r) {
            ps[r] += __shfl_xor(ps[r], st, 64);
            pd[r] += __shfl_xor(pd[r], st, 64);
        }
    }
    if (mrow == 0) {
        #pragma unroll
        for (int r = 0; r < 4; ++r) {
            a2p[wave][kg * 4 + r][0] = ps[r];
            a2p[wave][kg * 4 + r][1] = pd[r];
        }
    }
    __syncthreads();
    if (t < 16) {
        float ss = a2p[0][t][0] + a2p[1][t][0] + a2p[2][t][0] + a2p[3][t][0];
        float dd = a2p[0][t][1] + a2p[1][t][1] + a2p[2][t][1] + a2p[3][t][1];
        a2s[row0 + t] = ss; a2d[row0 + t] = dd;
    }
}

// ==== k_conv2: fused softmax+message; wave per node; coalesced x2[d][c] write ====
__global__ __launch_bounds__(256) void k_conv2(
    const int* __restrict__ cnt, const int* __restrict__ esrc, const float* __restrict__ h2,
    const float* __restrict__ a2s, const float* __restrict__ a2d, const float* __restrict__ b2,
    float* __restrict__ x2) {
    int t = threadIdx.x;
    int wave = t >> 6, lane = t & 63;
    int d = blockIdx.x * 4 + wave;
    int cn = cnt[d];
    const int* ep = esrc + (size_t)d * CAP;
    float adv = a2d[d];
    int eg = lane >> 4, c4 = (lane & 15) * 4;

    float den = 0.f;
    float4_ acc = {0.f, 0.f, 0.f, 0.f};
    for (int e = eg; e < cn; e += 4) {
        int s = ep[e];
        float ea = __expf(lrelu02(a2s[s] + adv));
        float4_ hv = *(const float4_*)(h2 + (size_t)s * EMB + c4);
        den += ea;
        acc.x += ea * hv.x; acc.y += ea * hv.y; acc.z += ea * hv.z; acc.w += ea * hv.w;
    }
    #pragma unroll
    for (int st = 16; st < 64; st <<= 1) {
        den   += __shfl_xor(den, st, 64);
        acc.x += __shfl_xor(acc.x, st, 64);
        acc.y += __shfl_xor(acc.y, st, 64);
        acc.z += __shfl_xor(acc.z, st, 64);
        acc.w += __shfl_xor(acc.w, st, 64);
    }
    if (eg == 0) {
        float inv = 1.f / den;
        float4_ o;
        o.x = elu1(acc.x * inv + b2[c4 + 0]);
        o.y = elu1(acc.y * inv + b2[c4 + 1]);
        o.z = elu1(acc.z * inv + b2[c4 + 2]);
        o.w = elu1(acc.w * inv + b2[c4 + 3]);
        *(float4_*)(x2 + (size_t)d * EMB + c4) = o;   // 256 B contiguous per node
    }
}

// ==== k_mlp1: x2 natural layout is [b][k]; k uniform per wave; 128 blocks ====
__global__ __launch_bounds__(256) void k_mlp1(const float* __restrict__ x2,
                                              const float* __restrict__ w1,
                                              float* __restrict__ y1part) {
    __shared__ float red[NB * HID];
    int t = threadIdx.x;
    int wave = t >> 6, lane = t & 63;
    int j2 = lane * 2;
    float2_ acc[NB];
    #pragma unroll
    for (int b = 0; b < NB; ++b) acc[b] = (float2_){0.f, 0.f};

    for (int k = blockIdx.x * 4 + wave; k < KTOT; k += MLP1B * 4) {
        int kk = __builtin_amdgcn_readfirstlane(k);
        float2_ w = *(const float2_*)(w1 + (size_t)kk * HID + j2);
        const float* xr = x2 + kk;            // x2[b*64000 + kk] -> wave-uniform s_loads
        #pragma unroll
        for (int b = 0; b < NB; ++b) {
            float xv = xr[(size_t)b * KTOT];
            acc[b].x += xv * w.x;
            acc[b].y += xv * w.y;
        }
    }
    for (int w = 0; w < 4; ++w) {
        if (wave == w) {
            #pragma unroll
            for (int b = 0; b < NB; ++b) {
                if (w == 0) {
                    red[b * HID + j2]     = acc[b].x;
                    red[b * HID + j2 + 1] = acc[b].y;
                } else {
                    red[b * HID + j2]     += acc[b].x;
                    red[b * HID + j2 + 1] += acc[b].y;
                }
            }
        }
        __syncthreads();
    }
    float* yp = y1part + (size_t)blockIdx.x * (NB * HID);
    for (int idx = t; idx < NB * HID; idx += 256)
        yp[idx] = red[idx];
}

// ==== k_tail (16 blocks): reduce y1part (redundant) -> y2 (redundant) -> out slice ====
__global__ __launch_bounds__(256) void k_tail(
    const float* __restrict__ y1part, const float* __restrict__ mb1,
    const float* __restrict__ mw2, const float* __restrict__ mb2,
    const float* __restrict__ ow, const float* __restrict__ ob,
    float* __restrict__ out) {
    __shared__ float y1[NB * HID];
    __shared__ float y2s[NB * HID];
    __shared__ float oacc[4][64][NB];
    int t = threadIdx.x;

    // phase 1: reduce 128 partials + bias + relu (coalesced column reads)
    for (int idx = t; idx < NB * HID; idx += 256) {
        float s = 0.f;
        #pragma unroll 8
        for (int p = 0; p < MLP1B; ++p)
            s += y1part[(size_t)p * (NB * HID) + idx];
        y1[idx] = fmaxf(s + mb1[idx & 127], 0.f);
    }
    __syncthreads();

    // phase 2: y2 = relu(y1 @ mw2 + mb2), full 16x128, redundant per block
    #pragma unroll
    for (int i = 0; i < 8; ++i) {
        int o = t + i * 256;
        int b = o >> 7, j = o & 127;
        float acc = mb2[j];
        for (int k = 0; k < HID; ++k) acc += y1[b * HID + k] * mw2[k * HID + j];
        y2s[o] = fmaxf(acc, 0.f);
    }
    __syncthreads();

    // phase 3: out slice n in [bid*64, +64); j split 4 ways across waves
    int qj = t >> 6, nl = t & 63;
    int n = blockIdx.x * 64 + nl;
    float acc[NB];
    #pragma unroll
    for (int b = 0; b < NB; ++b) acc[b] = 0.f;
    if (n < NN) {
        for (int j = qj * 32; j < qj * 32 + 32; ++j) {
            float w = ow[j * NN + n];
            #pragma unroll
            for (int b = 0; b < NB; ++b) acc[b] += y2s[b * HID + j] * w;
        }
    }
    #pragma unroll
    for (int b = 0; b < NB; ++b) oacc[qj][nl][b] = acc[b];
    __syncthreads();
    if (qj == 0 && n < NN) {
        float obv = ob[n];
        #pragma unroll
        for (int b = 0; b < NB; ++b) {
            float s = oacc[0][nl][b] + oacc[1][nl][b] + oacc[2][nl][b] + oacc[3][nl][b] + obv;
            out[b * NN + n] = 1.f / (1.f + __expf(-s));
        }
    }
}

extern "C" void kernel_launch(void* const* d_in, const int* in_sizes, int n_in,
                              void* d_out, int out_size, void* d_ws, size_t ws_size,
                              hipStream_t stream) {
    const float* actions = (const float*)d_in[0];
    const float* nf      = (const float*)d_in[1];
    const int*   ei      = (const int*)d_in[2];
    const float* W1      = (const float*)d_in[3];
    const float* as1w    = (const float*)d_in[4];
    const float* ad1w    = (const float*)d_in[5];
    const float* b1      = (const float*)d_in[6];
    const float* W2      = (const float*)d_in[7];
    const float* as2w    = (const float*)d_in[8];
    const float* ad2w    = (const float*)d_in[9];
    const float* b2      = (const float*)d_in[10];
    const float* mw1     = (const float*)d_in[11];
    const float* mb1     = (const float*)d_in[12];
    const float* mw2     = (const float*)d_in[13];
    const float* mb2     = (const float*)d_in[14];
    const float* ow      = (const float*)d_in[15];
    const float* ob      = (const float*)d_in[16];
    float* out = (float*)d_out;

    // workspace carve (all segments 16B-aligned)
    float* f = (float*)d_ws;
    float* x4    = f;  f += (size_t)NT * 4;
    float* h2    = f;  f += (size_t)NT * EMB;
    float* x2    = f;  f += (size_t)NT * EMB;
    float* as1   = f;  f += NT * 8;
    float* ad1   = f;  f += NT * 8;
    float* a2s   = f;  f += NT;
    float* a2d   = f;  f += NT;
    float* y1part= f;  f += (size_t)MLP1B * NB * HID;
    ushort_t* w2f = (ushort_t*)f;                 // 4*32*64*8 = 65536 fp16
    int* ip = (int*)(w2f + 65536);
    int* cnt  = ip; ip += NT;
    int* esrc = ip; ip += (size_t)NT * CAP;

    k_prep0<<<32, 1024, 0, stream>>>(actions, nf, W1, as1w, ad1w, W2, x4, as1, ad1, w2f, cnt);
    k_fillslots<<<(ETOT + 255) / 256, 256, 0, stream>>>(ei, cnt, esrc);
    k_conv1h2<<<NT / 16, 256, 0, stream>>>(cnt, esrc, x4, as1, ad1, W1, b1, w2f,
                                           as2w, ad2w, h2, a2s, a2d);
    k_conv2<<<NT / 4, 256, 0, stream>>>(cnt, esrc, h2, a2s, a2d, b2, x2);
    k_mlp1<<<MLP1B, 256, 0, stream>>>(x2, mw1, y1part);
    k_tail<<<16, 256, 0, stream>>>(y1part, mb1, mw2, mb2, ow, ob, out);
}

// Round 9
// 240.085 us; speedup vs baseline: 5.6188x; 1.2394x over previous
//
#include <hip/hip_runtime.h>
#include <math.h>

#define NB 16
#define NN 1000
#define NT 16000          // NB*NN total nodes
#define NE 16000          // edges per graph
#define EBASE 256000      // NB*NE
#define ETOT 272000       // EBASE + NT self loops
#define F1 1024           // H1*C1
#define EMB 64
#define HID 128
#define KTOT 64000        // N*EMB mlp1 reduction length
#define MLP1B 128         // mlp1 stage-A block count
#define CAP 96            // per-node edge slot capacity (max degree ~56 at 4sigma; safe)

typedef unsigned short ushort_t;
typedef unsigned int uint_t;
typedef __attribute__((ext_vector_type(8))) _Float16 half8;
typedef __attribute__((ext_vector_type(4))) float float4_;
typedef __attribute__((ext_vector_type(2))) float float2_;
typedef __attribute__((ext_vector_type(2))) uint_t uint2_;

// ---- scrambled edge mapping (faithful to reference row-major reshape) ----
__device__ __forceinline__ int src_of(const int* ei, int j) {
    if (j < EBASE) return ei[j] + (j / 32000) * 1000;
    return j - EBASE;
}
__device__ __forceinline__ int dst_of(const int* ei, int j) {
    if (j < EBASE) return ei[EBASE + j] + (8 + j / 32000) * 1000;
    return j - EBASE;
}

__device__ __forceinline__ float lrelu02(float r) { return r >= 0.f ? r : 0.2f * r; }
__device__ __forceinline__ float elu1(float v)    { return v > 0.f ? v : expm1f(v); }
__device__ __forceinline__ ushort_t f2h(float f) {
    _Float16 h = (_Float16)f;           // v_cvt_f16_f32, RTE
    union { _Float16 h; ushort_t u; } c; c.h = h; return c.u;
}

// ==== k_prep0 (32 blocks x 1024): zero cnt/y1sum | nodeinit (bid 0..15, wa redundant)
//      | W2 -> fragment-major fp16 w2f (bid 16..31) ====
__global__ __launch_bounds__(1024) void k_prep0(
    const float* __restrict__ actions, const float* __restrict__ nf,
    const float* __restrict__ W1, const float* __restrict__ as1w, const float* __restrict__ ad1w,
    const float* __restrict__ W2,
    float* __restrict__ x4, float* __restrict__ as1, float* __restrict__ ad1,
    ushort_t* __restrict__ w2f, int* __restrict__ cnt, float* __restrict__ y1sum) {
    __shared__ float tile[64][65];
    __shared__ float was[24], wad[24];
    int bid = blockIdx.x, t = threadIdx.x;

    // zero edge counters + y1sum accumulator (stream-ordered before users)
    int zi = bid * 1024 + t;
    if (zi < NT) cnt[zi] = 0;
    if (bid == 31) { y1sum[t] = 0.f; y1sum[t + 1024] = 0.f; }

    if (bid < 16) {
        // wa[3][8] precontract, redundant per block
        if (t < 24) {
            int k = t / 8, h = t % 8;
            float ss = 0.f, dd = 0.f;
            for (int c = 0; c < 128; ++c) {
                float w = W1[k * F1 + h * 128 + c];
                ss += w * as1w[h * 128 + c];
                dd += w * ad1w[h * 128 + c];
            }
            was[t] = ss; wad[t] = dd;
        }
        __syncthreads();
        int n = bid * 1000 + t;
        if (t < 1000) {
            float x0 = actions[n * 2 + 0];
            float x1v = actions[n * 2 + 1];
            float x2v = nf[n];
            float4_ xv = {x0, x1v, x2v, 0.f};
            *(float4_*)(x4 + (size_t)n * 4) = xv;
            #pragma unroll
            for (int h = 0; h < 8; ++h) {
                as1[n * 8 + h] = x0 * was[h] + x1v * was[8 + h] + x2v * was[16 + h];
                ad1[n * 8 + h] = x0 * wad[h] + x1v * wad[8 + h] + x2v * wad[16 + h];
            }
        }
    } else {
        // W2 rows k0..k0+63 -> w2f fragment-major (layout verified r7/r8)
        int k0 = (bid - 16) * 64;
        int c = t & 63, g = t >> 6;       // g in 0..15
        for (int r = g; r < 64; r += 16)
            tile[r][c] = W2[(size_t)(k0 + r) * 64 + c];
        __syncthreads();
        if (t < 512) {
            int q = t;
            int t4 = q >> 7, ksl = (q >> 6) & 1, l8 = q & 63;
            int kg = l8 >> 4, mrow = l8 & 15;
            int n = t4 * 16 + mrow;
            int kloc = ksl * 32 + kg * 8;
            size_t base = (((size_t)t4 * 32 + (k0 >> 5) + ksl) * 64 + l8) * 8;
            #pragma unroll
            for (int j = 0; j < 8; ++j)
                w2f[base + j] = f2h(tile[kloc + j][n]);
        }
    }
}

// ==== k_fillslots: single-pass edge bucketing (atomic slot per dst node) ====
__global__ void k_fillslots(const int* __restrict__ ei, int* __restrict__ cnt,
                            int* __restrict__ esrc) {
    int j = blockIdx.x * blockDim.x + threadIdx.x;
    if (j >= ETOT) return;
    int dv = dst_of(ei, j);
    int slot = atomicAdd(&cnt[dv], 1);
    if (slot < CAP) esrc[(size_t)dv * CAP + slot] = src_of(ei, j);
}

// ==== k_conv1h2: fused conv1 + h2-GEMM (x1 tile lives only in LDS) ====
__global__ __launch_bounds__(256) void k_conv1h2(
    const int* __restrict__ cnt, const int* __restrict__ esrc, const float* __restrict__ x4,
    const float* __restrict__ as1, const float* __restrict__ ad1,
    const float* __restrict__ W1, const float* __restrict__ b1,
    const ushort_t* __restrict__ w2f,
    const float* __restrict__ as2w, const float* __restrict__ ad2w,
    float* __restrict__ h2, float* __restrict__ a2s, float* __restrict__ a2d) {
    __shared__ ushort_t x1t[16][1032];   // padded: row stride 2064 B -> 2-way-bank (free)
    __shared__ float smb[16][8][3];
    __shared__ float a2p[4][16][2];
    int t = threadIdx.x, wave = t >> 6, lane = t & 63;

    // W1/b1 slice in registers: channels 4t..4t+3 (loaded once, L2-hot)
    float4_ w0 = *(const float4_*)(W1 + t * 4);
    float4_ w1r = *(const float4_*)(W1 + F1 + t * 4);
    float4_ w2r = *(const float4_*)(W1 + 2 * F1 + t * 4);
    float4_ bb = *(const float4_*)(b1 + t * 4);

    // ---- phase A: edge softmax (4 nodes/wave, 16 lanes/node) ----
    int g = lane >> 4, lg = lane & 15, eslot = lg >> 3, h = lg & 7;
    int nd0 = wave * 4 + g;
    int d = blockIdx.x * 16 + nd0;
    int cn = cnt[d];
    const int* ep = esrc + (size_t)d * CAP;
    float adv = ad1[d * 8 + h];
    float den = 0.f, s0 = 0.f, s1 = 0.f, s2 = 0.f;
    for (int e = eslot; e < cn; e += 2) {
        int s = ep[e];
        float ea = __expf(lrelu02(as1[s * 8 + h] + adv));
        float4_ xv = *(const float4_*)(x4 + (size_t)s * 4);
        den += ea; s0 += ea * xv.x; s1 += ea * xv.y; s2 += ea * xv.z;
    }
    den += __shfl_xor(den, 8, 64);
    s0  += __shfl_xor(s0, 8, 64);
    s1  += __shfl_xor(s1, 8, 64);
    s2  += __shfl_xor(s2, 8, 64);
    if (eslot == 0) {
        float inv = 1.f / den;
        smb[nd0][h][0] = s0 * inv;
        smb[nd0][h][1] = s1 * inv;
        smb[nd0][h][2] = s2 * inv;
    }
    __syncthreads();

    // ---- phase B: x1 = elu(xs @ W1 + b1) -> LDS fp16 ----
    int hh = t >> 5;
    #pragma unroll 4
    for (int nd = 0; nd < 16; ++nd) {
        float c0 = smb[nd][hh][0], c1 = smb[nd][hh][1], c2 = smb[nd][hh][2];
        float v0 = c0 * w0.x + c1 * w1r.x + c2 * w2r.x + bb.x;
        float v1 = c0 * w0.y + c1 * w1r.y + c2 * w2r.y + bb.y;
        float v2 = c0 * w0.z + c1 * w1r.z + c2 * w2r.z + bb.z;
        float v3 = c0 * w0.w + c1 * w1r.w + c2 * w2r.w + bb.w;
        v0 = elu1(v0); v1 = elu1(v1); v2 = elu1(v2); v3 = elu1(v3);
        uint2_ pk;
        pk.x = (uint_t)f2h(v0) | ((uint_t)f2h(v1) << 16);
        pk.y = (uint_t)f2h(v2) | ((uint_t)f2h(v3) << 16);
        *(uint2_*)(&x1t[nd][t * 4]) = pk;
    }
    __syncthreads();

    // ---- phase C: 16x64 = x1t(16x1024) @ W2, wave owns out-cols wave*16..+15 ----
    int mrow = lane & 15, kg = lane >> 4;
    const ushort_t* bp = w2f + ((size_t)wave * 32 * 64 + lane) * 8;
    float4_ acc = {0.f, 0.f, 0.f, 0.f};
    #pragma unroll 8
    for (int ks = 0; ks < 32; ++ks) {
        half8 a = *(const half8*)(&x1t[mrow][kg * 8 + ks * 32]);
        half8 b = *(const half8*)(bp + (size_t)ks * 512);
        acc = __builtin_amdgcn_mfma_f32_16x16x32_f16(a, b, acc, 0, 0, 0);
    }
    int row0 = blockIdx.x * 16;
    #pragma unroll
    for (int r = 0; r < 4; ++r)
        h2[(size_t)(row0 + kg * 4 + r) * EMB + wave * 16 + mrow] = acc[r];

    // a2s/a2d = h2 . att2 (fused epilogue)
    float sw = as2w[wave * 16 + mrow], dw = ad2w[wave * 16 + mrow];
    float ps[4], pd[4];
    #pragma unroll
    for (int r = 0; r < 4; ++r) { ps[r] = acc[r] * sw; pd[r] = acc[r] * dw; }
    #pragma unroll
    for (int st = 1; st < 16; st <<= 1) {
        #pragma unroll
        for (int r = 0; r < 4; ++r) {
            ps[r] += __shfl_xor(ps[r], st, 64);
            pd[r] += __shfl_xor(pd[r], st, 64);
        }
    }
    if (mrow == 0) {
        #pragma unroll
        for (int r = 0; r < 4; ++r) {
            a2p[wave][kg * 4 + r][0] = ps[r];
            a2p[wave][kg * 4 + r][1] = pd[r];
        }
    }
    __syncthreads();
    if (t < 16) {
        float ss = a2p[0][t][0] + a2p[1][t][0] + a2p[2][t][0] + a2p[3][t][0];
        float dd = a2p[0][t][1] + a2p[1][t][1] + a2p[2][t][1] + a2p[3][t][1];
        a2s[row0 + t] = ss; a2d[row0 + t] = dd;
    }
}

// ==== k_conv2: fused softmax+message; wave per node; coalesced x2[d][c] write ====
__global__ __launch_bounds__(256) void k_conv2(
    const int* __restrict__ cnt, const int* __restrict__ esrc, const float* __restrict__ h2,
    const float* __restrict__ a2s, const float* __restrict__ a2d, const float* __restrict__ b2,
    float* __restrict__ x2) {
    int t = threadIdx.x;
    int wave = t >> 6, lane = t & 63;
    int d = blockIdx.x * 4 + wave;
    int cn = cnt[d];
    const int* ep = esrc + (size_t)d * CAP;
    float adv = a2d[d];
    int eg = lane >> 4, c4 = (lane & 15) * 4;

    float den = 0.f;
    float4_ acc = {0.f, 0.f, 0.f, 0.f};
    for (int e = eg; e < cn; e += 4) {
        int s = ep[e];
        float ea = __expf(lrelu02(a2s[s] + adv));
        float4_ hv = *(const float4_*)(h2 + (size_t)s * EMB + c4);
        den += ea;
        acc.x += ea * hv.x; acc.y += ea * hv.y; acc.z += ea * hv.z; acc.w += ea * hv.w;
    }
    #pragma unroll
    for (int st = 16; st < 64; st <<= 1) {
        den   += __shfl_xor(den, st, 64);
        acc.x += __shfl_xor(acc.x, st, 64);
        acc.y += __shfl_xor(acc.y, st, 64);
        acc.z += __shfl_xor(acc.z, st, 64);
        acc.w += __shfl_xor(acc.w, st, 64);
    }
    if (eg == 0) {
        float inv = 1.f / den;
        float4_ o;
        o.x = elu1(acc.x * inv + b2[c4 + 0]);
        o.y = elu1(acc.y * inv + b2[c4 + 1]);
        o.z = elu1(acc.z * inv + b2[c4 + 2]);
        o.w = elu1(acc.w * inv + b2[c4 + 3]);
        *(float4_*)(x2 + (size_t)d * EMB + c4) = o;   // 256 B contiguous per node
    }
}

// ==== k_mlp1: x2 natural layout is [b][k]; k uniform per wave; 128 blocks.
//      Block-reduce in LDS, then 2048 atomicAdds into y1sum (no y1part). ====
__global__ __launch_bounds__(256) void k_mlp1(const float* __restrict__ x2,
                                              const float* __restrict__ w1,
                                              float* __restrict__ y1sum) {
    __shared__ float red[NB * HID];
    int t = threadIdx.x;
    int wave = t >> 6, lane = t & 63;
    int j2 = lane * 2;
    float2_ acc[NB];
    #pragma unroll
    for (int b = 0; b < NB; ++b) acc[b] = (float2_){0.f, 0.f};

    for (int k = blockIdx.x * 4 + wave; k < KTOT; k += MLP1B * 4) {
        int kk = __builtin_amdgcn_readfirstlane(k);
        float2_ w = *(const float2_*)(w1 + (size_t)kk * HID + j2);
        const float* xr = x2 + kk;            // x2[b*64000 + kk] -> wave-uniform s_loads
        #pragma unroll
        for (int b = 0; b < NB; ++b) {
            float xv = xr[(size_t)b * KTOT];
            acc[b].x += xv * w.x;
            acc[b].y += xv * w.y;
        }
    }
    for (int w = 0; w < 4; ++w) {
        if (wave == w) {
            #pragma unroll
            for (int b = 0; b < NB; ++b) {
                if (w == 0) {
                    red[b * HID + j2]     = acc[b].x;
                    red[b * HID + j2 + 1] = acc[b].y;
                } else {
                    red[b * HID + j2]     += acc[b].x;
                    red[b * HID + j2 + 1] += acc[b].y;
                }
            }
        }
        __syncthreads();
    }
    for (int idx = t; idx < NB * HID; idx += 256)
        atomicAdd(&y1sum[idx], red[idx]);
}

// ==== k_tail (64 blocks): y1sum (8 KB, L2-hot) -> y2 (redundant) -> out 16-col slice ====
__global__ __launch_bounds__(256) void k_tail(
    const float* __restrict__ y1sum, const float* __restrict__ mb1,
    const float* __restrict__ mw2, const float* __restrict__ mb2,
    const float* __restrict__ ow, const float* __restrict__ ob,
    float* __restrict__ out) {
    __shared__ float y1[NB * HID];
    __shared__ float y2s[NB * HID];
    __shared__ float oacc[16][16][17];   // [jg][nl][b], padded -> <=2-way bank
    int t = threadIdx.x;

    // phase 1: bias + relu on the pre-reduced y1sum (8 KB)
    for (int idx = t; idx < NB * HID; idx += 256)
        y1[idx] = fmaxf(y1sum[idx] + mb1[idx & 127], 0.f);
    __syncthreads();

    // phase 2: y2 = relu(y1 @ mw2 + mb2), full 16x128, redundant per block
    #pragma unroll
    for (int i = 0; i < 8; ++i) {
        int o = t + i * 256;
        int b = o >> 7, j = o & 127;
        float acc = mb2[j];
        for (int k = 0; k < HID; ++k) acc += y1[b * HID + k] * mw2[k * HID + j];
        y2s[o] = fmaxf(acc, 0.f);
    }
    __syncthreads();

    // phase 3: out slice n in [bid*16, +16); j split 16 ways (8 j each)
    int nl = t & 15, jg = t >> 4;
    int n = blockIdx.x * 16 + nl;
    float acc[NB];
    #pragma unroll
    for (int b = 0; b < NB; ++b) acc[b] = 0.f;
    if (n < NN) {
        #pragma unroll
        for (int jj = 0; jj < 8; ++jj) {
            int j = jg * 8 + jj;
            float w = ow[j * NN + n];
            #pragma unroll
            for (int b = 0; b < NB; ++b) acc[b] += y2s[b * HID + j] * w;
        }
    }
    #pragma unroll
    for (int b = 0; b < NB; ++b) oacc[jg][nl][b] = acc[b];
    __syncthreads();
    // reduce over jg: thread t -> (b = t>>4, nl2 = t&15)
    int b = t >> 4, nl2 = t & 15;
    float s = 0.f;
    #pragma unroll
    for (int q = 0; q < 16; ++q) s += oacc[q][nl2][b];
    int n2 = blockIdx.x * 16 + nl2;
    if (n2 < NN)
        out[b * NN + n2] = 1.f / (1.f + __expf(-(s + ob[n2])));
}

extern "C" void kernel_launch(void* const* d_in, const int* in_sizes, int n_in,
                              void* d_out, int out_size, void* d_ws, size_t ws_size,
                              hipStream_t stream) {
    const float* actions = (const float*)d_in[0];
    const float* nf      = (const float*)d_in[1];
    const int*   ei      = (const int*)d_in[2];
    const float* W1      = (const float*)d_in[3];
    const float* as1w    = (const float*)d_in[4];
    const float* ad1w    = (const float*)d_in[5];
    const float* b1      = (const float*)d_in[6];
    const float* W2      = (const float*)d_in[7];
    const float* as2w    = (const float*)d_in[8];
    const float* ad2w    = (const float*)d_in[9];
    const float* b2      = (const float*)d_in[10];
    const float* mw1     = (const float*)d_in[11];
    const float* mb1     = (const float*)d_in[12];
    const float* mw2     = (const float*)d_in[13];
    const float* mb2     = (const float*)d_in[14];
    const float* ow      = (const float*)d_in[15];
    const float* ob      = (const float*)d_in[16];
    float* out = (float*)d_out;

    // workspace carve (all segments 16B-aligned)
    float* f = (float*)d_ws;
    float* x4    = f;  f += (size_t)NT * 4;
    float* h2    = f;  f += (size_t)NT * EMB;
    float* x2    = f;  f += (size_t)NT * EMB;
    float* as1   = f;  f += NT * 8;
    float* ad1   = f;  f += NT * 8;
    float* a2s   = f;  f += NT;
    float* a2d   = f;  f += NT;
    float* y1sum = f;  f += NB * HID;
    ushort_t* w2f = (ushort_t*)f;                 // 4*32*64*8 = 65536 fp16
    int* ip = (int*)(w2f + 65536);
    int* cnt  = ip; ip += NT;
    int* esrc = ip; ip += (size_t)NT * CAP;

    k_prep0<<<32, 1024, 0, stream>>>(actions, nf, W1, as1w, ad1w, W2, x4, as1, ad1, w2f, cnt, y1sum);
    k_fillslots<<<(ETOT + 255) / 256, 256, 0, stream>>>(ei, cnt, esrc);
    k_conv1h2<<<NT / 16, 256, 0, stream>>>(cnt, esrc, x4, as1, ad1, W1, b1, w2f,
                                           as2w, ad2w, h2, a2s, a2d);
    k_conv2<<<NT / 4, 256, 0, stream>>>(cnt, esrc, h2, a2s, a2d, b2, x2);
    k_mlp1<<<MLP1B, 256, 0, stream>>>(x2, mw1, y1sum);
    k_tail<<<64, 256, 0, stream>>>(y1sum, mb1, mw2, mb2, ow, ob, out);
}

// Round 10
// 204.186 us; speedup vs baseline: 6.6067x; 1.1758x over previous
//
#include <hip/hip_runtime.h>
#include <math.h>

#define NB 16
#define NN 1000
#define NT 16000          // NB*NN total nodes
#define NE 16000          // edges per graph
#define EBASE 256000      // NB*NE
#define ETOT 272000       // EBASE + NT self loops
#define F1 1024           // H1*C1
#define EMB 64
#define HID 128
#define KTOT 64000        // N*EMB mlp1 reduction length
#define MLP1B 1024        // mlp1 stage-A block count (16 waves/CU)
#define NREP 8            // y1sum replicas (atomic contention: 128 blocks/address)
#define CAP 96            // per-node edge slot capacity

typedef unsigned short ushort_t;
typedef unsigned int uint_t;
typedef __attribute__((ext_vector_type(8))) _Float16 half8;
typedef __attribute__((ext_vector_type(4))) float float4_;
typedef __attribute__((ext_vector_type(2))) float float2_;
typedef __attribute__((ext_vector_type(2))) uint_t uint2_;

// ---- scrambled edge mapping (faithful to reference row-major reshape) ----
__device__ __forceinline__ int src_of(const int* ei, int j) {
    if (j < EBASE) return ei[j] + (j / 32000) * 1000;
    return j - EBASE;
}
__device__ __forceinline__ int dst_of(const int* ei, int j) {
    if (j < EBASE) return ei[EBASE + j] + (8 + j / 32000) * 1000;
    return j - EBASE;
}

__device__ __forceinline__ float lrelu02(float r) { return r >= 0.f ? r : 0.2f * r; }
__device__ __forceinline__ float elu1(float v)    { return v > 0.f ? v : expm1f(v); }
__device__ __forceinline__ ushort_t f2h(float f) {
    _Float16 h = (_Float16)f;           // v_cvt_f16_f32, RTE
    union { _Float16 h; ushort_t u; } c; c.h = h; return c.u;
}

// ==== k_prep0 (32 blocks x 1024): zero cnt/y1rep | nodeinit (bid 0..15, wa redundant)
//      | W2 -> fragment-major fp16 w2f (bid 16..31) ====
__global__ __launch_bounds__(1024) void k_prep0(
    const float* __restrict__ actions, const float* __restrict__ nf,
    const float* __restrict__ W1, const float* __restrict__ as1w, const float* __restrict__ ad1w,
    const float* __restrict__ W2,
    float* __restrict__ x4, float* __restrict__ as1, float* __restrict__ ad1,
    ushort_t* __restrict__ w2f, int* __restrict__ cnt, float* __restrict__ y1rep) {
    __shared__ float tile[64][65];
    __shared__ float was[24], wad[24];
    int bid = blockIdx.x, t = threadIdx.x;

    // zero edge counters + y1 replica accumulators (stream-ordered before users)
    int zi = bid * 1024 + t;
    if (zi < NT) cnt[zi] = 0;
    if (bid >= 16) y1rep[(size_t)(bid - 16) * 1024 + t] = 0.f;   // 16K floats

    if (bid < 16) {
        // wa[3][8] precontract, redundant per block
        if (t < 24) {
            int k = t / 8, h = t % 8;
            float ss = 0.f, dd = 0.f;
            for (int c = 0; c < 128; ++c) {
                float w = W1[k * F1 + h * 128 + c];
                ss += w * as1w[h * 128 + c];
                dd += w * ad1w[h * 128 + c];
            }
            was[t] = ss; wad[t] = dd;
        }
        __syncthreads();
        int n = bid * 1000 + t;
        if (t < 1000) {
            float x0 = actions[n * 2 + 0];
            float x1v = actions[n * 2 + 1];
            float x2v = nf[n];
            float4_ xv = {x0, x1v, x2v, 0.f};
            *(float4_*)(x4 + (size_t)n * 4) = xv;
            #pragma unroll
            for (int h = 0; h < 8; ++h) {
                as1[n * 8 + h] = x0 * was[h] + x1v * was[8 + h] + x2v * was[16 + h];
                ad1[n * 8 + h] = x0 * wad[h] + x1v * wad[8 + h] + x2v * wad[16 + h];
            }
        }
    } else {
        // W2 rows k0..k0+63 -> w2f fragment-major (layout verified r7/r8)
        int k0 = (bid - 16) * 64;
        int c = t & 63, g = t >> 6;       // g in 0..15
        for (int r = g; r < 64; r += 16)
            tile[r][c] = W2[(size_t)(k0 + r) * 64 + c];
        __syncthreads();
        if (t < 512) {
            int q = t;
            int t4 = q >> 7, ksl = (q >> 6) & 1, l8 = q & 63;
            int kg = l8 >> 4, mrow = l8 & 15;
            int n = t4 * 16 + mrow;
            int kloc = ksl * 32 + kg * 8;
            size_t base = (((size_t)t4 * 32 + (k0 >> 5) + ksl) * 64 + l8) * 8;
            #pragma unroll
            for (int j = 0; j < 8; ++j)
                w2f[base + j] = f2h(tile[kloc + j][n]);
        }
    }
}

// ==== k_fillslots: single-pass edge bucketing (atomic slot per dst node) ====
__global__ void k_fillslots(const int* __restrict__ ei, int* __restrict__ cnt,
                            int* __restrict__ esrc) {
    int j = blockIdx.x * blockDim.x + threadIdx.x;
    if (j >= ETOT) return;
    int dv = dst_of(ei, j);
    int slot = atomicAdd(&cnt[dv], 1);
    if (slot < CAP) esrc[(size_t)dv * CAP + slot] = src_of(ei, j);
}

// ==== k_conv1h2: fused conv1 + h2-GEMM (x1 tile lives only in LDS) ====
__global__ __launch_bounds__(256) void k_conv1h2(
    const int* __restrict__ cnt, const int* __restrict__ esrc, const float* __restrict__ x4,
    const float* __restrict__ as1, const float* __restrict__ ad1,
    const float* __restrict__ W1, const float* __restrict__ b1,
    const ushort_t* __restrict__ w2f,
    const float* __restrict__ as2w, const float* __restrict__ ad2w,
    float* __restrict__ h2, float* __restrict__ a2s, float* __restrict__ a2d) {
    __shared__ ushort_t x1t[16][1032];   // padded: row stride 2064 B -> 2-way-bank (free)
    __shared__ float smb[16][8][3];
    __shared__ float a2p[4][16][2];
    int t = threadIdx.x, wave = t >> 6, lane = t & 63;

    // W1/b1 slice in registers: channels 4t..4t+3 (loaded once, L2-hot)
    float4_ w0 = *(const float4_*)(W1 + t * 4);
    float4_ w1r = *(const float4_*)(W1 + F1 + t * 4);
    float4_ w2r = *(const float4_*)(W1 + 2 * F1 + t * 4);
    float4_ bb = *(const float4_*)(b1 + t * 4);

    // ---- phase A: edge softmax (4 nodes/wave, 16 lanes/node) ----
    int g = lane >> 4, lg = lane & 15, eslot = lg >> 3, h = lg & 7;
    int nd0 = wave * 4 + g;
    int d = blockIdx.x * 16 + nd0;
    int cn = cnt[d];
    const int* ep = esrc + (size_t)d * CAP;
    float adv = ad1[d * 8 + h];
    float den = 0.f, s0 = 0.f, s1 = 0.f, s2 = 0.f;
    for (int e = eslot; e < cn; e += 2) {
        int s = ep[e];
        float ea = __expf(lrelu02(as1[s * 8 + h] + adv));
        float4_ xv = *(const float4_*)(x4 + (size_t)s * 4);
        den += ea; s0 += ea * xv.x; s1 += ea * xv.y; s2 += ea * xv.z;
    }
    den += __shfl_xor(den, 8, 64);
    s0  += __shfl_xor(s0, 8, 64);
    s1  += __shfl_xor(s1, 8, 64);
    s2  += __shfl_xor(s2, 8, 64);
    if (eslot == 0) {
        float inv = 1.f / den;
        smb[nd0][h][0] = s0 * inv;
        smb[nd0][h][1] = s1 * inv;
        smb[nd0][h][2] = s2 * inv;
    }
    __syncthreads();

    // ---- phase B: x1 = elu(xs @ W1 + b1) -> LDS fp16 ----
    int hh = t >> 5;
    #pragma unroll 4
    for (int nd = 0; nd < 16; ++nd) {
        float c0 = smb[nd][hh][0], c1 = smb[nd][hh][1], c2 = smb[nd][hh][2];
        float v0 = c0 * w0.x + c1 * w1r.x + c2 * w2r.x + bb.x;
        float v1 = c0 * w0.y + c1 * w1r.y + c2 * w2r.y + bb.y;
        float v2 = c0 * w0.z + c1 * w1r.z + c2 * w2r.z + bb.z;
        float v3 = c0 * w0.w + c1 * w1r.w + c2 * w2r.w + bb.w;
        v0 = elu1(v0); v1 = elu1(v1); v2 = elu1(v2); v3 = elu1(v3);
        uint2_ pk;
        pk.x = (uint_t)f2h(v0) | ((uint_t)f2h(v1) << 16);
        pk.y = (uint_t)f2h(v2) | ((uint_t)f2h(v3) << 16);
        *(uint2_*)(&x1t[nd][t * 4]) = pk;
    }
    __syncthreads();

    // ---- phase C: 16x64 = x1t(16x1024) @ W2, wave owns out-cols wave*16..+15 ----
    int mrow = lane & 15, kg = lane >> 4;
    const ushort_t* bp = w2f + ((size_t)wave * 32 * 64 + lane) * 8;
    float4_ acc = {0.f, 0.f, 0.f, 0.f};
    #pragma unroll 8
    for (int ks = 0; ks < 32; ++ks) {
        half8 a = *(const half8*)(&x1t[mrow][kg * 8 + ks * 32]);
        half8 b = *(const half8*)(bp + (size_t)ks * 512);
        acc = __builtin_amdgcn_mfma_f32_16x16x32_f16(a, b, acc, 0, 0, 0);
    }
    int row0 = blockIdx.x * 16;
    #pragma unroll
    for (int r = 0; r < 4; ++r)
        h2[(size_t)(row0 + kg * 4 + r) * EMB + wave * 16 + mrow] = acc[r];

    // a2s/a2d = h2 . att2 (fused epilogue)
    float sw = as2w[wave * 16 + mrow], dw = ad2w[wave * 16 + mrow];
    float ps[4], pd[4];
    #pragma unroll
    for (int r = 0; r < 4; ++r) { ps[r] = acc[r] * sw; pd[r] = acc[r] * dw; }
    #pragma unroll
    for (int st = 1; st < 16; st <<= 1) {
        #pragma unroll
        for (int r = 0; r < 4; ++r) {
            ps[r] += __shfl_xor(ps[r], st, 64);
            pd[r] += __shfl_xor(pd[r], st, 64);
        }
    }
    if (mrow == 0) {
        #pragma unroll
        for (int r = 0; r < 4; ++r) {
            a2p[wave][kg * 4 + r][0] = ps[r];
            a2p[wave][kg * 4 + r][1] = pd[r];
        }
    }
    __syncthreads();
    if (t < 16) {
        float ss = a2p[0][t][0] + a2p[1][t][0] + a2p[2][t][0] + a2p[3][t][0];
        float dd = a2p[0][t][1] + a2p[1][t][1] + a2p[2][t][1] + a2p[3][t][1];
        a2s[row0 + t] = ss; a2d[row0 + t] = dd;
    }
}

// ==== k_conv2: fused softmax+message; wave per node; coalesced x2[d][c] write ====
__global__ __launch_bounds__(256) void k_conv2(
    const int* __restrict__ cnt, const int* __restrict__ esrc, const float* __restrict__ h2,
    const float* __restrict__ a2s, const float* __restrict__ a2d, const float* __restrict__ b2,
    float* __restrict__ x2) {
    int t = threadIdx.x;
    int wave = t >> 6, lane = t & 63;
    int d = blockIdx.x * 4 + wave;
    int cn = cnt[d];
    const int* ep = esrc + (size_t)d * CAP;
    float adv = a2d[d];
    int eg = lane >> 4, c4 = (lane & 15) * 4;

    float den = 0.f;
    float4_ acc = {0.f, 0.f, 0.f, 0.f};
    for (int e = eg; e < cn; e += 4) {
        int s = ep[e];
        float ea = __expf(lrelu02(a2s[s] + adv));
        float4_ hv = *(const float4_*)(h2 + (size_t)s * EMB + c4);
        den += ea;
        acc.x += ea * hv.x; acc.y += ea * hv.y; acc.z += ea * hv.z; acc.w += ea * hv.w;
    }
    #pragma unroll
    for (int st = 16; st < 64; st <<= 1) {
        den   += __shfl_xor(den, st, 64);
        acc.x += __shfl_xor(acc.x, st, 64);
        acc.y += __shfl_xor(acc.y, st, 64);
        acc.z += __shfl_xor(acc.z, st, 64);
        acc.w += __shfl_xor(acc.w, st, 64);
    }
    if (eg == 0) {
        float inv = 1.f / den;
        float4_ o;
        o.x = elu1(acc.x * inv + b2[c4 + 0]);
        o.y = elu1(acc.y * inv + b2[c4 + 1]);
        o.z = elu1(acc.z * inv + b2[c4 + 2]);
        o.w = elu1(acc.w * inv + b2[c4 + 3]);
        *(float4_*)(x2 + (size_t)d * EMB + c4) = o;   // 256 B contiguous per node
    }
}

// ==== k_mlp1: 1024 blocks (16 waves/CU); LDS-reduce then atomics into replica ====
__global__ __launch_bounds__(256) void k_mlp1(const float* __restrict__ x2,
                                              const float* __restrict__ w1,
                                              float* __restrict__ y1rep) {
    __shared__ float red[NB * HID];
    int t = threadIdx.x;
    int wave = t >> 6, lane = t & 63;
    int j2 = lane * 2;
    float2_ acc[NB];
    #pragma unroll
    for (int b = 0; b < NB; ++b) acc[b] = (float2_){0.f, 0.f};

    for (int k = blockIdx.x * 4 + wave; k < KTOT; k += MLP1B * 4) {
        int kk = __builtin_amdgcn_readfirstlane(k);
        float2_ w = *(const float2_*)(w1 + (size_t)kk * HID + j2);
        const float* xr = x2 + kk;            // x2[b*64000 + kk] -> wave-uniform s_loads
        #pragma unroll
        for (int b = 0; b < NB; ++b) {
            float xv = xr[(size_t)b * KTOT];
            acc[b].x += xv * w.x;
            acc[b].y += xv * w.y;
        }
    }
    for (int w = 0; w < 4; ++w) {
        if (wave == w) {
            #pragma unroll
            for (int b = 0; b < NB; ++b) {
                if (w == 0) {
                    red[b * HID + j2]     = acc[b].x;
                    red[b * HID + j2 + 1] = acc[b].y;
                } else {
                    red[b * HID + j2]     += acc[b].x;
                    red[b * HID + j2 + 1] += acc[b].y;
                }
            }
        }
        __syncthreads();
    }
    float* yp = y1rep + (size_t)(blockIdx.x & (NREP - 1)) * (NB * HID);
    for (int idx = t; idx < NB * HID; idx += 256)
        atomicAdd(&yp[idx], red[idx]);
}

// ==== k_tail (64 blocks): reduce 8 replicas -> y2 (redundant) -> out 16-col slice ====
__global__ __launch_bounds__(256) void k_tail(
    const float* __restrict__ y1rep, const float* __restrict__ mb1,
    const float* __restrict__ mw2, const float* __restrict__ mb2,
    const float* __restrict__ ow, const float* __restrict__ ob,
    float* __restrict__ out) {
    __shared__ float y1[NB * HID];
    __shared__ float y2s[NB * HID];
    __shared__ float oacc[16][16][17];   // [jg][nl][b], padded -> <=2-way bank
    int t = threadIdx.x;

    // phase 1: reduce NREP replicas + bias + relu (64 KB, L2-hot)
    for (int idx = t; idx < NB * HID; idx += 256) {
        float s = 0.f;
        #pragma unroll
        for (int r = 0; r < NREP; ++r)
            s += y1rep[(size_t)r * (NB * HID) + idx];
        y1[idx] = fmaxf(s + mb1[idx & 127], 0.f);
    }
    __syncthreads();

    // phase 2: y2 = relu(y1 @ mw2 + mb2), full 16x128, redundant per block
    #pragma unroll
    for (int i = 0; i < 8; ++i) {
        int o = t + i * 256;
        int b = o >> 7, j = o & 127;
        float acc = mb2[j];
        for (int k = 0; k < HID; ++k) acc += y1[b * HID + k] * mw2[k * HID + j];
        y2s[o] = fmaxf(acc, 0.f);
    }
    __syncthreads();

    // phase 3: out slice n in [bid*16, +16); j split 16 ways (8 j each)
    int nl = t & 15, jg = t >> 4;
    int n = blockIdx.x * 16 + nl;
    float acc[NB];
    #pragma unroll
    for (int b = 0; b < NB; ++b) acc[b] = 0.f;
    if (n < NN) {
        #pragma unroll
        for (int jj = 0; jj < 8; ++jj) {
            int j = jg * 8 + jj;
            float w = ow[j * NN + n];
            #pragma unroll
            for (int b = 0; b < NB; ++b) acc[b] += y2s[b * HID + j] * w;
        }
    }
    #pragma unroll
    for (int b = 0; b < NB; ++b) oacc[jg][nl][b] = acc[b];
    __syncthreads();
    // reduce over jg: thread t -> (b = t>>4, nl2 = t&15)
    int b = t >> 4, nl2 = t & 15;
    float s = 0.f;
    #pragma unroll
    for (int q = 0; q < 16; ++q) s += oacc[q][nl2][b];
    int n2 = blockIdx.x * 16 + nl2;
    if (n2 < NN)
        out[b * NN + n2] = 1.f / (1.f + __expf(-(s + ob[n2])));
}

extern "C" void kernel_launch(void* const* d_in, const int* in_sizes, int n_in,
                              void* d_out, int out_size, void* d_ws, size_t ws_size,
                              hipStream_t stream) {
    const float* actions = (const float*)d_in[0];
    const float* nf      = (const float*)d_in[1];
    const int*   ei      = (const int*)d_in[2];
    const float* W1      = (const float*)d_in[3];
    const float* as1w    = (const float*)d_in[4];
    const float* ad1w    = (const float*)d_in[5];
    const float* b1      = (const float*)d_in[6];
    const float* W2      = (const float*)d_in[7];
    const float* as2w    = (const float*)d_in[8];
    const float* ad2w    = (const float*)d_in[9];
    const float* b2      = (const float*)d_in[10];
    const float* mw1     = (const float*)d_in[11];
    const float* mb1     = (const float*)d_in[12];
    const float* mw2     = (const float*)d_in[13];
    const float* mb2     = (const float*)d_in[14];
    const float* ow      = (const float*)d_in[15];
    const float* ob      = (const float*)d_in[16];
    float* out = (float*)d_out;

    // workspace carve (all segments 16B-aligned)
    float* f = (float*)d_ws;
    float* x4    = f;  f += (size_t)NT * 4;
    float* h2    = f;  f += (size_t)NT * EMB;
    float* x2    = f;  f += (size_t)NT * EMB;
    float* as1   = f;  f += NT * 8;
    float* ad1   = f;  f += NT * 8;
    float* a2s   = f;  f += NT;
    float* a2d   = f;  f += NT;
    float* y1rep = f;  f += (size_t)NREP * NB * HID;
    ushort_t* w2f = (ushort_t*)f;                 // 4*32*64*8 = 65536 fp16
    int* ip = (int*)(w2f + 65536);
    int* cnt  = ip; ip += NT;
    int* esrc = ip; ip += (size_t)NT * CAP;

    k_prep0<<<32, 1024, 0, stream>>>(actions, nf, W1, as1w, ad1w, W2, x4, as1, ad1, w2f, cnt, y1rep);
    k_fillslots<<<(ETOT + 255) / 256, 256, 0, stream>>>(ei, cnt, esrc);
    k_conv1h2<<<NT / 16, 256, 0, stream>>>(cnt, esrc, x4, as1, ad1, W1, b1, w2f,
                                           as2w, ad2w, h2, a2s, a2d);
    k_conv2<<<NT / 4, 256, 0, stream>>>(cnt, esrc, h2, a2s, a2d, b2, x2);
    k_mlp1<<<MLP1B, 256, 0, stream>>>(x2, mw1, y1rep);
    k_tail<<<64, 256, 0, stream>>>(y1rep, mb1, mw2, mb2, ow, ob, out);
}